// Round 6
// baseline (461.915 us; speedup 1.0000x reference)
//
#include <hip/hip_runtime.h>
#include <hip/hip_bf16.h>

#define N_NODES 8192
#define IN_F 512
#define OUT_F 128
#define KP 16                     // k-partitions (blockIdx-split, R0-proven)
#define KT_PER 16                 // k-tiles of 32 cols per partition
#define NWORDS (N_NODES / 32)     // packed words per adj row = 256
#define LOG2E 1.4426950408889634f

typedef unsigned short u16;
typedef unsigned int u32;
typedef short s16x8 __attribute__((ext_vector_type(8)));
typedef float f32x4 __attribute__((ext_vector_type(4)));
typedef u32 u32x4 __attribute__((ext_vector_type(4)));

__device__ __forceinline__ u16 f2bf(float f) {
    union { float f; unsigned u; } x; x.f = f;
    unsigned r = x.u + 0x7FFFu + ((x.u >> 16) & 1u);
    return (u16)(r >> 16);
}

// HW pack: v_cvt_pk_bf16_f32 (rne) -> u32 (lo=a, hi=b)
__device__ __forceinline__ u32 packbf2(float a, float b) {
    __hip_bfloat162 h = __float22bfloat162_rn(make_float2(a, b));
    u32 u; __builtin_memcpy(&u, &h, 4);
    return u;
}

// edge weight: exp(sigmoid(alpha)) or 0 if masked
__device__ __forceinline__ float edge_p(float wh1, float w2, int keep) {
    float alpha = wh1 + w2;
    float e = exp2f(-LOG2E * alpha);
    float s = __builtin_amdgcn_rcpf(1.0f + e);
    float p = exp2f(LOG2E * s);
    return keep ? p : 0.0f;
}

// ---- K0 "prep": three independent jobs fused into one dispatch.
//  blocks [0, 8192):    pack adj int32 -> 1-bit bitmap (256 MB -> 8 MB)
//  blocks [8192, 8448): repack W fp32 -> bf16 MFMA B-fragment layout
//  blocks [8448, 8450): Wa1 = W@a1, Wa2 = W@a2
__global__ __launch_bounds__(256)
void prep(const int* __restrict__ adj, const float* __restrict__ W,
          const float* __restrict__ a1, const float* __restrict__ a2,
          u32* __restrict__ Pk, u16* __restrict__ W_frag,
          float* __restrict__ Wa1, float* __restrict__ Wa2) {
    int b = blockIdx.x;
    int tid = threadIdx.x;
    if (b < 8192) {
        int gid = b * 256 + tid;                  // word index, 2M total
        const int* src = adj + (size_t)gid * 32;
        u32 bits = 0;
        #pragma unroll
        for (int t = 0; t < 8; t++) {
            int4 v = *(const int4*)(src + t * 4);
            bits |= (u32)(v.x > 0) << (t * 4 + 0);
            bits |= (u32)(v.y > 0) << (t * 4 + 1);
            bits |= (u32)(v.z > 0) << (t * 4 + 2);
            bits |= (u32)(v.w > 0) << (t * 4 + 3);
        }
        Pk[gid] = bits;
    } else if (b < 8448) {
        int t2 = (b - 8192) * 256 + tid;          // 0..65535
        int j = t2 & 7;
        int lane = (t2 >> 3) & 63;
        int nt = (t2 >> 9) & 7;
        int kt = t2 >> 12;
        int k = kt * 32 + (lane >> 4) * 8 + j;
        int n = nt * 16 + (lane & 15);
        W_frag[t2] = f2bf(W[k * OUT_F + n]);
    } else {
        int k = (b - 8448) * 256 + tid;           // 0..511
        float s1 = 0.f, s2 = 0.f;
        #pragma unroll 8
        for (int n = 0; n < OUT_F; n++) {
            float w = W[k * OUT_F + n];
            s1 += w * a1[n];
            s2 += w * a2[n];
        }
        Wa1[k] = s1; Wa2[k] = s2;
    }
}

// ---- K1: h = X@W (bf16 MFMA), scatter h to B-frag layout; Wh = X@Wa (fp32).
// R6: 512 blocks x 512 thr (8 waves, nt0 = wave, ONE acc each) -> 4096 waves
// = 4 waves/SIMD, 2x the TLP of the old 4-wave shape. X rows L1-shared
// across the block's 8 waves; all loads one-kt-ahead register prefetch.
__global__ __launch_bounds__(512)
void gemm_h(const float* __restrict__ X, const u16* __restrict__ W_frag,
            const float* __restrict__ Wa1, const float* __restrict__ Wa2,
            float* __restrict__ Wh1, float* __restrict__ Wh2,
            u16* __restrict__ h_frag) {
    int tid = threadIdx.x;
    int wave = tid >> 6;          // 0..7 = nt
    int lane = tid & 63;
    int quad = lane >> 4;
    int lid = lane & 15;
    int rbase = blockIdx.x * 16;
    const float* xrow = X + (size_t)(rbase + lid) * IN_F;
    const s16x8* Wf = (const s16x8*)W_frag;
    f32x4 acc = {};
    float p1 = 0.f, p2 = 0.f;
    int nt0 = wave;

    // prologue prefetch: kt = 0
    int k0p = quad * 8;
    float4 X0 = *(const float4*)(xrow + k0p);
    float4 X1 = *(const float4*)(xrow + k0p + 4);
    s16x8 B0 = Wf[nt0 * 64 + lane];
    float4 A0 = {}, A1 = {}, C0 = {}, C1 = {};
    if (wave == 0) {
        A0 = *(const float4*)(Wa1 + k0p); A1 = *(const float4*)(Wa1 + k0p + 4);
        C0 = *(const float4*)(Wa2 + k0p); C1 = *(const float4*)(Wa2 + k0p + 4);
    }

    #pragma unroll 1
    for (int kt = 0; kt < 16; kt++) {
        float4 x0 = X0, x1 = X1;
        s16x8 b0 = B0;
        float4 wa = A0, wb = A1, wc = C0, wd = C1;
        int ktn = (kt + 1 < 16) ? kt + 1 : kt;    // clamp (no OOB)
        int k0n = ktn * 32 + quad * 8;
        X0 = *(const float4*)(xrow + k0n);
        X1 = *(const float4*)(xrow + k0n + 4);
        B0 = Wf[(ktn * 8 + nt0) * 64 + lane];
        if (wave == 0) {
            A0 = *(const float4*)(Wa1 + k0n); A1 = *(const float4*)(Wa1 + k0n + 4);
            C0 = *(const float4*)(Wa2 + k0n); C1 = *(const float4*)(Wa2 + k0n + 4);
        }

        u32x4 uv;
        uv.x = packbf2(x0.x, x0.y); uv.y = packbf2(x0.z, x0.w);
        uv.z = packbf2(x1.x, x1.y); uv.w = packbf2(x1.z, x1.w);
        s16x8 a = __builtin_bit_cast(s16x8, uv);
        if (wave == 0) {
            p1 += x0.x*wa.x + x0.y*wa.y + x0.z*wa.z + x0.w*wa.w
                + x1.x*wb.x + x1.y*wb.y + x1.z*wb.z + x1.w*wb.w;
            p2 += x0.x*wc.x + x0.y*wc.y + x0.z*wc.z + x0.w*wc.w
                + x1.x*wd.x + x1.y*wd.y + x1.z*wd.z + x1.w*wd.w;
        }
        acc = __builtin_amdgcn_mfma_f32_16x16x32_bf16(a, b0, acc, 0, 0, 0);
    }

    #pragma unroll
    for (int reg = 0; reg < 4; reg++) {
        int row = rbase + quad * 4 + reg;
        int ktile = row >> 5, kl = row & 31;
        int lane2 = (kl >> 3) * 16 + lid, j2 = kl & 7;
        h_frag[(size_t)((ktile * 8 + nt0) * 64 + lane2) * 8 + j2] = f2bf(acc[reg]);
    }
    if (wave == 0) {
        p1 += __shfl_xor(p1, 16, 64); p1 += __shfl_xor(p1, 32, 64);
        p2 += __shfl_xor(p2, 16, 64); p2 += __shfl_xor(p2, 32, 64);
        if (lane < 16) { Wh1[rbase + lid] = p1; Wh2[rbase + lid] = p2; }
    }
}

// ---- K2: attention on the PACKED adjacency — the R0-proven independent-wave
// shape: 64 rtiles x KP kparts = 1024 blocks x 256 thr (4096 waves, no LDS,
// no barriers). Wave owns 32 rows x 512-col k-stripe; Pk words group-
// prefetched one 4-kt group ahead; Wh2/h_frag loaded in-iteration (L1/L2-
// shared across the many concurrent waves of the same kh).
__global__ __launch_bounds__(256)
void attn_kernel(const u32* __restrict__ Pk, const float* __restrict__ Wh1,
                 const float* __restrict__ Wh2, const u16* __restrict__ h_frag,
                 float* __restrict__ out_part, float* __restrict__ sum_part) {
    int tid = threadIdx.x;
    int wave = tid >> 6;
    int lane = tid & 63;
    int quad = lane >> 4;
    int lid = lane & 15;
    int rtile = blockIdx.x >> 4;
    int kh = blockIdx.x & (KP - 1);
    int rbase = rtile * 128 + wave * 32;
    int r0 = rbase + lid, r1 = r0 + 16;

    float wh10 = Wh1[r0], wh11 = Wh1[r1];
    f32x4 acc0[8] = {}, acc1[8] = {};
    float ps0 = 0.f, ps1 = 0.f;
    const s16x8* Hf = (const s16x8*)h_frag;
    const u32* prow0 = Pk + (size_t)r0 * NWORDS;
    const u32* prow1 = Pk + (size_t)r1 * NWORDS;
    const int kt0 = kh * KT_PER;

    // prologue: group 0's packed words (4 k-tiles per group)
    u32x4 PA = *(const u32x4*)(prow0 + kt0);
    u32x4 PB = *(const u32x4*)(prow1 + kt0);

    auto step = [&](int i, u32 pw0, u32 pw1) {
        int kt = kt0 + i;
        int k0 = kt * 32 + quad * 8;
        float4 w20 = *(const float4*)(Wh2 + k0);
        float4 w21 = *(const float4*)(Wh2 + k0 + 4);
        u32 w0 = pw0 >> (quad * 8);
        u32 w1 = pw1 >> (quad * 8);

        float e0 = edge_p(wh10, w20.x, (w0 >> 0) & 1);
        float e1 = edge_p(wh10, w20.y, (w0 >> 1) & 1);
        float e2 = edge_p(wh10, w20.z, (w0 >> 2) & 1);
        float e3 = edge_p(wh10, w20.w, (w0 >> 3) & 1);
        float e4 = edge_p(wh10, w21.x, (w0 >> 4) & 1);
        float e5 = edge_p(wh10, w21.y, (w0 >> 5) & 1);
        float e6 = edge_p(wh10, w21.z, (w0 >> 6) & 1);
        float e7 = edge_p(wh10, w21.w, (w0 >> 7) & 1);
        ps0 += ((e0 + e1) + (e2 + e3)) + ((e4 + e5) + (e6 + e7));
        u32x4 uv0;
        uv0.x = packbf2(e0, e1); uv0.y = packbf2(e2, e3);
        uv0.z = packbf2(e4, e5); uv0.w = packbf2(e6, e7);

        float f0 = edge_p(wh11, w20.x, (w1 >> 0) & 1);
        float f1 = edge_p(wh11, w20.y, (w1 >> 1) & 1);
        float f2 = edge_p(wh11, w20.z, (w1 >> 2) & 1);
        float f3 = edge_p(wh11, w20.w, (w1 >> 3) & 1);
        float f4 = edge_p(wh11, w21.x, (w1 >> 4) & 1);
        float f5 = edge_p(wh11, w21.y, (w1 >> 5) & 1);
        float f6 = edge_p(wh11, w21.z, (w1 >> 6) & 1);
        float f7 = edge_p(wh11, w21.w, (w1 >> 7) & 1);
        ps1 += ((f0 + f1) + (f2 + f3)) + ((f4 + f5) + (f6 + f7));
        u32x4 uv1;
        uv1.x = packbf2(f0, f1); uv1.y = packbf2(f2, f3);
        uv1.z = packbf2(f4, f5); uv1.w = packbf2(f6, f7);

        s16x8 af0 = __builtin_bit_cast(s16x8, uv0);
        s16x8 af1 = __builtin_bit_cast(s16x8, uv1);

        #pragma unroll
        for (int nt = 0; nt < 8; nt++) {
            s16x8 b = Hf[(kt * 8 + nt) * 64 + lane];
            acc0[nt] = __builtin_amdgcn_mfma_f32_16x16x32_bf16(af0, b, acc0[nt], 0, 0, 0);
            acc1[nt] = __builtin_amdgcn_mfma_f32_16x16x32_bf16(af1, b, acc1[nt], 0, 0, 0);
        }
    };

    #pragma unroll 1
    for (int g = 0; g < KT_PER / 4; g++) {
        u32x4 cPA = PA, cPB = PB;   // consume copies (static element access)
        int gb = kt0 + ((g + 1 < KT_PER / 4) ? (g + 1) * 4 : 0);  // wrap
        PA = *(const u32x4*)(prow0 + gb);
        PB = *(const u32x4*)(prow1 + gb);
        step(g * 4 + 0, cPA.x, cPB.x);
        step(g * 4 + 1, cPA.y, cPB.y);
        step(g * 4 + 2, cPA.z, cPB.z);
        step(g * 4 + 3, cPA.w, cPB.w);
    }

    ps0 += __shfl_xor(ps0, 16, 64); ps0 += __shfl_xor(ps0, 32, 64);
    ps1 += __shfl_xor(ps1, 16, 64); ps1 += __shfl_xor(ps1, 32, 64);
    if (quad == 0) {
        sum_part[(size_t)kh * N_NODES + r0] = ps0;
        sum_part[(size_t)kh * N_NODES + r1] = ps1;
    }

    #pragma unroll
    for (int nt = 0; nt < 8; nt++) {
        #pragma unroll
        for (int reg = 0; reg < 4; reg++) {
            int row0 = rbase + quad * 4 + reg;
            int col = nt * 16 + lid;
            out_part[((size_t)kh * N_NODES + row0) * OUT_F + col] = acc0[nt][reg];
            out_part[((size_t)kh * N_NODES + row0 + 16) * OUT_F + col] = acc1[nt][reg];
        }
    }
}

// ---- K3: out = (sum_k part_k) / (sum_k rowsum_k)
__global__ void finalize(const float* __restrict__ out_part,
                         const float* __restrict__ sum_part,
                         float* __restrict__ out) {
    int gid = blockIdx.x * 256 + threadIdx.x;
    int i = gid >> 7;
    float s = 0.f, v = 0.f;
    for (int kh = 0; kh < KP; kh++) {
        s += sum_part[(size_t)kh * N_NODES + i];
        v += out_part[(size_t)kh * N_NODES * OUT_F + gid];
    }
    out[gid] = v / s;
}

extern "C" void kernel_launch(void* const* d_in, const int* in_sizes, int n_in,
                              void* d_out, int out_size, void* d_ws, size_t ws_size,
                              hipStream_t stream) {
    const float* X   = (const float*)d_in[0];
    const int*   adj = (const int*)d_in[1];
    const float* W   = (const float*)d_in[2];
    const float* a1  = (const float*)d_in[3];
    const float* a2  = (const float*)d_in[4];

    char* ws = (char*)d_ws;
    float* Wh1 = (float*)(ws);                         // 32 KB
    float* Wh2 = (float*)(ws + (32 << 10));            // 32 KB
    float* Wa1 = (float*)(ws + (64 << 10));            // 2 KB
    float* Wa2 = (float*)(ws + (66 << 10));            // 2 KB
    u16* W_frag = (u16*)(ws + (128 << 10));            // 128 KB
    u16* h_frag = (u16*)(ws + (256 << 10));            // 2 MB (ends 2.25 MB)
    u32* Pk     = (u32*)(ws + ((size_t)4 << 20));      // 8 MB packed adj
    float* out_part = (float*)(ws + ((size_t)16 << 20));   // KP*4 MB = 64 MB
    float* sum_part = (float*)(ws + ((size_t)80 << 20));   // KP*32 KB
    float* out = (float*)d_out;

    hipLaunchKernelGGL(prep, dim3(8450), dim3(256), 0, stream,
                       adj, W, a1, a2, Pk, W_frag, Wa1, Wa2);
    hipLaunchKernelGGL(gemm_h, dim3(512), dim3(512), 0, stream,
                       X, W_frag, Wa1, Wa2, Wh1, Wh2, h_frag);
    hipLaunchKernelGGL(attn_kernel, dim3(64 * KP), dim3(256), 0, stream,
                       Pk, Wh1, Wh2, h_frag, out_part, sum_part);
    hipLaunchKernelGGL(finalize, dim3((N_NODES * OUT_F) / 256), dim3(256), 0, stream,
                       out_part, sum_part, out);
}